// Round 12
// baseline (4832.545 us; speedup 1.0000x reference)
//
#include <hip/hip_runtime.h>

#define T_LEN 1024
#define B_SZ  256
#define D_DIM 64
#define E_DIM 512
#define H_DIM 256

#define SA 552   // flow A-tile LDS stride (bf16 elems)
#define SH 264   // flow hid-tile LDS stride
#define SF 66    // flow stf stride (floats)
#define ROWB 1152  // esn LDS row stride BYTES (576 fp16)

#define FLOW_LDS (64*SA*2 + 64*SH*2 + 64*64*4 + 64*4 + 16*4)   // 121152 B

using short8 = __attribute__((ext_vector_type(8))) short;
using half8  = __attribute__((ext_vector_type(8))) _Float16;
using f32x4  = __attribute__((ext_vector_type(4))) float;
typedef unsigned long long ull;

static __device__ __forceinline__ unsigned short f2bf(float v) {
    unsigned u = __float_as_uint(v);
    u += 0x7FFFu + ((u >> 16) & 1u);   // RNE to bf16
    return (unsigned short)(u >> 16);
}
static __device__ __forceinline__ unsigned short f2h(float v) {
    _Float16 h = (_Float16)v;
    unsigned short u;
    __builtin_memcpy(&u, &h, 2);
    return u;
}
static __device__ __forceinline__ float h2f(unsigned short u) {
    _Float16 h;
    __builtin_memcpy(&h, &u, 2);
    return (float)h;
}
static __device__ __forceinline__ float fast_tanh(float x) {
    x = fminf(15.f, fmaxf(-15.f, x));
    float e = __expf(2.f * x);
    return (e - 1.f) / (e + 1.f);
}
// XOR bank swizzle within each 128B sub-block of a 1152B row (both-sides involution).
static __device__ __forceinline__ int rswz(int row, int byte_in_row) {
    return row * ROWB + (byte_in_row ^ ((row & 7) << 4));
}

// ---- Weight prep (R9 verified) ----
__global__ void prep_kernel(const float* __restrict__ W_in, const float* __restrict__ W_s,
                            const float* __restrict__ W_t, const float* __restrict__ W_res,
                            const float* __restrict__ W_inp, const float* __restrict__ x_seq,
                            unsigned short* __restrict__ W_inF, unsigned short* __restrict__ W_stF,
                            unsigned short* __restrict__ W_packo, unsigned short* __restrict__ x_h) {
    int idx = blockIdx.x * blockDim.x + threadIdx.x;
    int stride = gridDim.x * blockDim.x;
    const int total1 = 8 * 16 * 17 * 64 * 8;        // W_inF
    for (int i = idx; i < total1; i += stride) {
        int j    = i & 7;
        int lane = (i >> 3) & 63;
        int ks   = (i >> 9) % 17;
        int nt   = (i / (512 * 17)) & 15;
        int ls   = i / (512 * 17 * 16);
        int side = ls & 1, l = ls >> 1;
        int n = nt * 16 + (lane & 15);
        int k = ks * 32 + (lane >> 4) * 8 + j;
        int ksrc = (k < 32) ? (side == 0 ? 32 + k : k) : (k + 32);
        W_inF[i] = f2bf(W_in[(l * 576 + ksrc) * H_DIM + n]);
    }
    const int total2 = 8 * 4 * 8 * 64 * 8;          // W_stF
    for (int i = idx; i < total2; i += stride) {
        int j    = i & 7;
        int lane = (i >> 3) & 63;
        int ks   = (i >> 9) & 7;
        int nt   = (i >> 12) & 3;
        int ls   = i >> 14;
        int side = ls & 1, l = ls >> 1;
        int nst = nt * 16 + (lane & 15);
        int k   = ks * 32 + (lane >> 4) * 8 + j;
        int j32 = nst & 31;
        int d   = side ? (32 + j32) : j32;
        float v = (nst < 32) ? W_s[(l * H_DIM + k) * D_DIM + d] : W_t[(l * H_DIM + k) * D_DIM + d];
        W_stF[i] = f2bf(v);
    }
    const int total3 = E_DIM * 576;
    for (int i = idx; i < total3; i += stride) {
        int k = i % 576;
        int n = i / 576;
        float v = (k < E_DIM) ? W_res[n * E_DIM + k] : W_inp[(k - E_DIM) * E_DIM + n];
        W_packo[i] = f2h(v);
    }
    const int total4 = T_LEN * B_SZ * D_DIM;
    for (int i = idx; i < total4; i += stride)
        x_h[i] = f2h(x_seq[i]);
}

// ---- Phase 1: ESN (R8/R9 verified: swizzled LDS, flag protocol, 0 conflicts). ----
__launch_bounds__(256, 1)
__global__ void esn_kernel(const unsigned short* __restrict__ x_h,
                           const unsigned short* __restrict__ W_pack,
                           unsigned short* __restrict__ h_store /*bf16 [tc][B][E]*/,
                           unsigned short* __restrict__ h_buf   /*fp16 [2][B][E]*/,
                           unsigned int* __restrict__ ctr,
                           int t0, int tc) {
    const int bid  = blockIdx.x;
    const int g    = bid & 15;
    const int m    = bid >> 4;
    const int tid  = threadIdx.x;
    const int wave = tid >> 6;
    const int lane = tid & 63;
    const int arow = lane & 15;
    const int kq   = lane >> 4;
    const int r0   = g * 16;
    const int n0   = m * 64;
    const size_t HB = (size_t)B_SZ * E_DIM;
    unsigned int* gctr = ctr + g * 32;

    extern __shared__ char smem[];
    char* Wlb = smem;                 // [64][1152B] W-slice, swizzled
    char* hAb = smem + 64 * ROWB;     // [16][1152B] = [h(1024B) | x(128B)], swizzled

    {   // W-slice -> LDS (swizzled write; one-time)
        const int r  = tid & 63;
        const int c0 = (tid >> 6) * 18;
        #pragma unroll
        for (int u = 0; u < 18; ++u) {
            const int byte = 16 * (c0 + u);
            *reinterpret_cast<uint4*>(Wlb + rswz(r, byte)) =
                *reinterpret_cast<const uint4*>(
                    reinterpret_cast<const char*>(&W_pack[(size_t)(n0 + r) * 576]) + byte);
        }
    }

    const int srow = tid >> 4;
    const int seg  = tid & 15;
    const int xrow = tid >> 2, xc = tid & 3;

    for (int tl = 0; tl < tc; ++tl) {
        const int t = t0 + tl;
        const unsigned short* hb_r = h_buf + (size_t)(t & 1) * HB;
        unsigned short*       hb_w = h_buf + (size_t)((t & 1) ^ 1) * HB;

        uint4 xa = {0,0,0,0}, xb = {0,0,0,0};
        if (tid < 64) {
            const unsigned short* xp = &x_h[((size_t)t * B_SZ + r0 + xrow) * D_DIM + xc * 16];
            xa = *reinterpret_cast<const uint4*>(xp);
            xb = *reinterpret_cast<const uint4*>(xp + 8);
        }

        if (tid == 0) {
            while (__hip_atomic_fetch_add(gctr, 0u, __ATOMIC_RELAXED,
                                          __HIP_MEMORY_SCOPE_AGENT) < 8u * (unsigned)t)
                __builtin_amdgcn_s_sleep(1);
        }
        __syncthreads();
        asm volatile("" ::: "memory");

        ull hv[8];
        const ull* hrow = reinterpret_cast<const ull*>(&hb_r[(size_t)(r0 + srow) * E_DIM]);
        #pragma unroll
        for (int q = 0; q < 4; ++q) {
            const int c = seg + 16 * q;
            hv[2*q]   = __hip_atomic_load(hrow + 2*c,     __ATOMIC_RELAXED, __HIP_MEMORY_SCOPE_SYSTEM);
            hv[2*q+1] = __hip_atomic_load(hrow + 2*c + 1, __ATOMIC_RELAXED, __HIP_MEMORY_SCOPE_SYSTEM);
        }
        #pragma unroll
        for (int q = 0; q < 4; ++q) {
            const int c = seg + 16 * q;
            uint4 pk;
            __builtin_memcpy(&pk, &hv[2*q], 16);
            *reinterpret_cast<uint4*>(hAb + rswz(srow, 16 * c)) = pk;
        }
        if (tid < 64) {
            *reinterpret_cast<uint4*>(hAb + rswz(xrow, 1024 + 32 * xc))      = xa;
            *reinterpret_cast<uint4*>(hAb + rswz(xrow, 1024 + 32 * xc + 16)) = xb;
        }
        __syncthreads();

        if (tl == 0) {
            #pragma unroll
            for (int q = 0; q < 4; ++q) {
                const int c = seg + 16 * q;
                unsigned short o[8];
                #pragma unroll
                for (int j = 0; j < 4; ++j) o[j]     = f2bf(h2f((unsigned short)(hv[2*q]   >> (16 * j))));
                #pragma unroll
                for (int j = 0; j < 4; ++j) o[4 + j] = f2bf(h2f((unsigned short)(hv[2*q+1] >> (16 * j))));
                uint4 pk;
                __builtin_memcpy(&pk, o, 16);
                *reinterpret_cast<uint4*>(&h_store[(size_t)(r0 + srow) * E_DIM + 8 * c]) = pk;
            }
        }

        f32x4 accA = (f32x4){0.f, 0.f, 0.f, 0.f};
        f32x4 accB = (f32x4){0.f, 0.f, 0.f, 0.f};
        #pragma unroll
        for (int ks = 0; ks < 18; ++ks) {
            half8 a = *reinterpret_cast<const half8*>(hAb + rswz(arow, ks * 64 + kq * 16));
            half8 b = *reinterpret_cast<const half8*>(Wlb + rswz(wave * 16 + arow, ks * 64 + kq * 16));
            if (ks & 1) accB = __builtin_amdgcn_mfma_f32_16x16x32_f16(a, b, accB, 0, 0, 0);
            else        accA = __builtin_amdgcn_mfma_f32_16x16x32_f16(a, b, accA, 0, 0, 0);
        }
        f32x4 acc = accA + accB;

        const int ncol = n0 + wave * 16 + arow;
        #pragma unroll
        for (int i = 0; i < 4; ++i) {
            const int row = r0 + kq * 4 + i;
            float hvf = fast_tanh(acc[i]);
            __hip_atomic_store(&hb_w[(size_t)row * E_DIM + ncol], f2h(hvf),
                               __ATOMIC_RELAXED, __HIP_MEMORY_SCOPE_SYSTEM);
            if (tl + 1 < tc)
                h_store[((size_t)(tl + 1) * B_SZ + row) * E_DIM + ncol] = f2bf(hvf);
        }

        asm volatile("s_waitcnt vmcnt(0)" ::: "memory");
        __syncthreads();
        if (tid == 0)
            __hip_atomic_fetch_add(gctr, 1u, __ATOMIC_RELAXED, __HIP_MEMORY_SCOPE_AGENT);
    }
}

// ---- Phase 2: flow, M=64 tiles (R6-verified structure) + R9 fragment-linear W.
// 1 block/CU (121 KB LDS), 1 wave/SIMD -> full VGPR budget for ring-6 B prefetch.
__launch_bounds__(256, 1)
__global__ void flow_kernel(const float* __restrict__ x_seq, const unsigned short* __restrict__ h_store,
                            const unsigned short* __restrict__ W_inF, const unsigned short* __restrict__ W_stF,
                            const float* __restrict__ b_in, const float* __restrict__ b_s,
                            const float* __restrict__ b_t, const float* __restrict__ rescale_w,
                            const int* __restrict__ seq_len, float* __restrict__ ll_part,
                            int t0, int tc) {
    const int tt   = blockIdx.x >> 4;
    const int bt   = blockIdx.x & 15;
    const int tid  = threadIdx.x;
    const int wave = tid >> 6;
    const int lane = tid & 63;

    extern __shared__ char smemf[];
    unsigned short* abf   = reinterpret_cast<unsigned short*>(smemf);   // [64][SA]
    unsigned short* hidbf = abf + 64 * SA;                              // [64][SH]
    float* zf    = reinterpret_cast<float*>(hidbf + 64 * SH);           // [64][64]
    float* llacc = zf + 64 * 64;                                        // [64]
    float* llb   = llacc + 64;                                          // [16]
    float* stf   = reinterpret_cast<float*>(hidbf);                     // [64][SF] alias

    if (tid < 16) llb[tid] = 0.f;

    const int row4 = tid >> 2;   // 0..63
    const int c4   = tid & 3;

    for (int s = 0; s < 4; ++s) {
        const int trow = tt * 16 + 4 * s + (row4 >> 4);
        const int brow = bt * 16 + (row4 & 15);
        {   // stage z (fp32) and h (bf16) for 64 frames
            const float* xp = &x_seq[((size_t)(t0 + trow) * B_SZ + brow) * D_DIM + c4 * 16];
            #pragma unroll
            for (int q = 0; q < 4; ++q)
                *reinterpret_cast<float4*>(&zf[row4 * 64 + c4 * 16 + q * 4]) =
                    *reinterpret_cast<const float4*>(xp + q * 4);
            const unsigned short* hp = &h_store[((size_t)trow * B_SZ + brow) * E_DIM + c4 * 128];
            unsigned short* ap = &abf[row4 * SA + 32 + c4 * 128];
            #pragma unroll
            for (int q = 0; q < 16; ++q)
                *reinterpret_cast<uint4*>(ap + q * 8) = *reinterpret_cast<const uint4*>(hp + q * 8);
        }
        if (tid < 64) llacc[tid] = 0.f;
        __syncthreads();

        for (int stage = 0; stage < 8; ++stage) {
            const int l = 3 - (stage >> 1);
            const int side = stage & 1;
            const int ls = l * 2 + side;
            {   // build masked-z A-columns (k=0..31)
                #pragma unroll
                for (int q = 0; q < 8; ++q) {
                    int k = c4 * 8 + q;
                    int d = side ? k : (32 + k);
                    abf[row4 * SA + k] = f2bf(zf[row4 * 64 + d]);
                }
            }
            __syncthreads();

            // hid GEMM: M=64 K=544 N=256; fragment-linear coalesced B, ring-6
            const unsigned short* wbase =
                W_inF + ((size_t)(ls * 16 + wave * 4) * 17) * 512 + lane * 8;
            f32x4 acc[4][4];
            #pragma unroll
            for (int mt = 0; mt < 4; ++mt)
                #pragma unroll
                for (int nt = 0; nt < 4; ++nt)
                    acc[mt][nt] = (f32x4){0.f, 0.f, 0.f, 0.f};
            const int aoff = (lane & 15) * SA + 8 * (lane >> 4);
            short8 bb[6][4];
            #pragma unroll
            for (int p = 0; p < 6; ++p)
                #pragma unroll
                for (int nt = 0; nt < 4; ++nt)
                    bb[p][nt] = *reinterpret_cast<const short8*>(wbase + (size_t)nt * 8704 + p * 512);
            #pragma unroll
            for (int ks = 0; ks < 17; ++ks) {
                const int k0 = ks * 32;
                short8 am[4];
                #pragma unroll
                for (int mt = 0; mt < 4; ++mt)
                    am[mt] = *reinterpret_cast<const short8*>(&abf[mt * 16 * SA + aoff + k0]);
                #pragma unroll
                for (int nt = 0; nt < 4; ++nt)
                    #pragma unroll
                    for (int mt = 0; mt < 4; ++mt)
                        acc[mt][nt] = __builtin_amdgcn_mfma_f32_16x16x32_bf16(am[mt], bb[ks % 6][nt], acc[mt][nt], 0, 0, 0);
                if (ks + 6 < 17) {
                    #pragma unroll
                    for (int nt = 0; nt < 4; ++nt)
                        bb[ks % 6][nt] = *reinterpret_cast<const short8*>(
                            wbase + (size_t)nt * 8704 + (ks + 6) * 512);
                }
            }
            #pragma unroll
            for (int nt = 0; nt < 4; ++nt) {
                const int n = wave * 64 + nt * 16 + (lane & 15);
                const float bias = b_in[l * H_DIM + n];
                #pragma unroll
                for (int mt = 0; mt < 4; ++mt)
                    #pragma unroll
                    for (int i = 0; i < 4; ++i) {
                        const int row = mt * 16 + (lane >> 4) * 4 + i;
                        hidbf[row * SH + n] = f2bf(fast_tanh(acc[mt][nt][i] + bias));
                    }
            }
            __syncthreads();

            // slope|intercept GEMM: M=64 K=256 N=64; fragment-linear B, ring-2
            const unsigned short* wstb =
                W_stF + ((size_t)(ls * 4 + wave) * 8) * 512 + lane * 8;
            f32x4 acc2[4];
            #pragma unroll
            for (int mt = 0; mt < 4; ++mt) acc2[mt] = (f32x4){0.f, 0.f, 0.f, 0.f};
            const int hoff = (lane & 15) * SH + 8 * (lane >> 4);
            const int nst  = wave * 16 + (lane & 15);
            short8 bs0 = *reinterpret_cast<const short8*>(wstb);
            #pragma unroll
            for (int ks = 0; ks < 8; ++ks) {
                short8 bcur = bs0;
                if (ks + 1 < 8) bs0 = *reinterpret_cast<const short8*>(wstb + (ks + 1) * 512);
                const int k0 = ks * 32;
                #pragma unroll
                for (int mt = 0; mt < 4; ++mt) {
                    short8 a = *reinterpret_cast<const short8*>(&hidbf[mt * 16 * SH + hoff + k0]);
                    acc2[mt] = __builtin_amdgcn_mfma_f32_16x16x32_bf16(a, bcur, acc2[mt], 0, 0, 0);
                }
            }
            __syncthreads();   // hidbf reads done before stf (alias) writes
            {
                const int j = nst & 31;
                const int d = side ? (32 + j) : j;
                const bool is_s = (nst < 32);
                const float bias = is_s ? b_s[l * D_DIM + d] : b_t[l * D_DIM + d];
                const float rs = rescale_w[d];
                #pragma unroll
                for (int mt = 0; mt < 4; ++mt)
                    #pragma unroll
                    for (int i = 0; i < 4; ++i) {
                        const int row = mt * 16 + (lane >> 4) * 4 + i;
                        const float v = acc2[mt][i] + bias;
                        stf[row * SF + nst] = is_s ? (fast_tanh(v) * rs) : v;
                    }
            }
            __syncthreads();
            {   // z-update + wave-parallel log-det (4 threads/row, 8 dims each)
                float p = 0.f;
                #pragma unroll
                for (int q = 0; q < 8; ++q) {
                    const int j = c4 * 8 + q;
                    const int d = side ? (32 + j) : j;   // updated dims (matches W_stF prep)
                    const float sv = stf[row4 * SF + j];
                    const float iv = stf[row4 * SF + 32 + j];
                    zf[row4 * 64 + d] = (zf[row4 * 64 + d] - iv) * __expf(-sv);
                    p += sv;
                }
                p += __shfl_xor(p, 1);
                p += __shfl_xor(p, 2);
                if (c4 == 0) llacc[row4] -= p;
            }
            __syncthreads();
        } // stage

        {   // wave-parallel zsum + mask
            float zs = 0.f;
            #pragma unroll
            for (int q = 0; q < 16; ++q) {
                float z = zf[row4 * 64 + c4 * 16 + q];
                zs += z * z;
            }
            zs += __shfl_xor(zs, 1);
            zs += __shfl_xor(zs, 2);
            if (c4 == 0) {
                float ll = llacc[row4] - 0.5f * zs - 58.812066125f;   // 0.5*64*log(2*pi)
                llacc[row4] = ((t0 + trow) < seq_len[brow]) ? ll : 0.f;
            }
        }
        __syncthreads();
        if (tid < 16)
            llb[tid] += llacc[tid] + llacc[16 + tid] + llacc[32 + tid] + llacc[48 + tid];
        __syncthreads();
    } // subtiles

    if (tid < 16)
        ll_part[((t0 >> 4) + tt) * B_SZ + bt * 16 + tid] = llb[tid];
}

__global__ void reduce_kernel(const float* __restrict__ ll_part, float* __restrict__ out) {
    int b = threadIdx.x;
    float s = 0.f;
    #pragma unroll
    for (int tt = 0; tt < T_LEN / 16; ++tt) s += ll_part[tt * B_SZ + b];
    out[b] = s;
}

extern "C" void kernel_launch(void* const* d_in, const int* in_sizes, int n_in,
                              void* d_out, int out_size, void* d_ws, size_t ws_size,
                              hipStream_t stream) {
    const float* x_seq   = (const float*)d_in[0];
    const int*   seqlen  = (const int*)d_in[1];
    const float* W_in    = (const float*)d_in[3];
    const float* b_in    = (const float*)d_in[4];
    const float* W_s     = (const float*)d_in[5];
    const float* b_s     = (const float*)d_in[6];
    const float* W_t     = (const float*)d_in[7];
    const float* b_t     = (const float*)d_in[8];
    const float* rescale = (const float*)d_in[9];
    const float* W_res   = (const float*)d_in[10];
    const float* W_inp   = (const float*)d_in[11];

    char* ws = (char*)d_ws;
    size_t off = 0;
    unsigned short* W_inF  = (unsigned short*)(ws + off); off += (size_t)8 * 16 * 17 * 64 * 8 * 2;
    unsigned short* W_stF  = (unsigned short*)(ws + off); off += (size_t)8 * 4 * 8 * 64 * 8 * 2;
    unsigned short* W_pack = (unsigned short*)(ws + off); off += (size_t)E_DIM * 576 * 2;
    unsigned short* x_h    = (unsigned short*)(ws + off); off += (size_t)T_LEN * B_SZ * D_DIM * 2;
    float* ll_part = (float*)(ws + off); off += (size_t)(T_LEN / 16) * B_SZ * 4;
    unsigned short* h_buf  = (unsigned short*)(ws + off); off += (size_t)2 * B_SZ * E_DIM * 2;
    unsigned int* ctr = (unsigned int*)(ws + off); off += (size_t)16 * 32 * 4;
    unsigned short* h_store = (unsigned short*)(ws + off);

    size_t per_t = (size_t)B_SZ * E_DIM * 2;
    size_t rem = (ws_size > off) ? (ws_size - off) : 0;
    long long tcl = (long long)(rem / per_t);
    int tc = (int)((tcl > T_LEN) ? T_LEN : tcl);
    tc &= ~15;
    if (tc < 16) tc = 16;

    hipMemsetAsync(h_buf, 0, (size_t)2 * B_SZ * E_DIM * 2, stream);
    hipMemsetAsync(ctr, 0, (size_t)16 * 32 * 4, stream);

    prep_kernel<<<2048, 256, 0, stream>>>(W_in, W_s, W_t, W_res, W_inp, x_seq,
                                          W_inF, W_stF, W_pack, x_h);
    const int esn_lds = (64 + 16) * ROWB;   // 92,160 B: W-slice + hA, swizzled
    for (int t0 = 0; t0 < T_LEN; t0 += tc) {
        int cur = T_LEN - t0; if (cur > tc) cur = tc;
        esn_kernel<<<128, 256, esn_lds, stream>>>(x_h, W_pack, h_store, h_buf, ctr, t0, cur);
        flow_kernel<<<(cur / 16) * 16, 256, FLOW_LDS, stream>>>(x_seq, h_store, W_inF, W_stF,
                                                                b_in, b_s, b_t, rescale, seqlen,
                                                                ll_part, t0, cur);
    }
    reduce_kernel<<<1, B_SZ, 0, stream>>>(ll_part, (float*)d_out);
}

// Round 13
// 4005.220 us; speedup vs baseline: 1.2066x; 1.2066x over previous
//
#include <hip/hip_runtime.h>

#define T_LEN 1024
#define B_SZ  256
#define D_DIM 64
#define E_DIM 512
#define H_DIM 256

#define SA 552   // flow A-tile LDS stride (bf16 elems) — verified 2-way max
#define SH 264   // flow hid-tile LDS stride
#define SF 66    // flow stf stride (floats)
#define ROWB 1152  // esn LDS row stride BYTES (576 fp16)

#define FLOW_LDS (128*SA*2 + 32*SH*2 + 128*4)   // 158,720 B

using short8 = __attribute__((ext_vector_type(8))) short;
using half8  = __attribute__((ext_vector_type(8))) _Float16;
using f32x4  = __attribute__((ext_vector_type(4))) float;
typedef unsigned long long ull;

static __device__ __forceinline__ unsigned short f2bf(float v) {
    unsigned u = __float_as_uint(v);
    u += 0x7FFFu + ((u >> 16) & 1u);   // RNE to bf16
    return (unsigned short)(u >> 16);
}
static __device__ __forceinline__ unsigned short f2h(float v) {
    _Float16 h = (_Float16)v;
    unsigned short u;
    __builtin_memcpy(&u, &h, 2);
    return u;
}
static __device__ __forceinline__ float h2f(unsigned short u) {
    _Float16 h;
    __builtin_memcpy(&h, &u, 2);
    return (float)h;
}
static __device__ __forceinline__ float fast_tanh(float x) {
    x = fminf(15.f, fmaxf(-15.f, x));
    float e = __expf(2.f * x);
    return (e - 1.f) / (e + 1.f);
}
// XOR bank swizzle within each 128B sub-block of a 1152B row (both-sides involution).
static __device__ __forceinline__ int rswz(int row, int byte_in_row) {
    return row * ROWB + (byte_in_row ^ ((row & 7) << 4));
}

// ---- Weight prep (R9 verified) ----
__global__ void prep_kernel(const float* __restrict__ W_in, const float* __restrict__ W_s,
                            const float* __restrict__ W_t, const float* __restrict__ W_res,
                            const float* __restrict__ W_inp, const float* __restrict__ x_seq,
                            unsigned short* __restrict__ W_inF, unsigned short* __restrict__ W_stF,
                            unsigned short* __restrict__ W_packo, unsigned short* __restrict__ x_h) {
    int idx = blockIdx.x * blockDim.x + threadIdx.x;
    int stride = gridDim.x * blockDim.x;
    const int total1 = 8 * 16 * 17 * 64 * 8;        // W_inF
    for (int i = idx; i < total1; i += stride) {
        int j    = i & 7;
        int lane = (i >> 3) & 63;
        int ks   = (i >> 9) % 17;
        int nt   = (i / (512 * 17)) & 15;
        int ls   = i / (512 * 17 * 16);
        int side = ls & 1, l = ls >> 1;
        int n = nt * 16 + (lane & 15);
        int k = ks * 32 + (lane >> 4) * 8 + j;
        int ksrc = (k < 32) ? (side == 0 ? 32 + k : k) : (k + 32);
        W_inF[i] = f2bf(W_in[(l * 576 + ksrc) * H_DIM + n]);
    }
    const int total2 = 8 * 4 * 8 * 64 * 8;          // W_stF
    for (int i = idx; i < total2; i += stride) {
        int j    = i & 7;
        int lane = (i >> 3) & 63;
        int ks   = (i >> 9) & 7;
        int nt   = (i >> 12) & 3;
        int ls   = i >> 14;
        int side = ls & 1, l = ls >> 1;
        int nst = nt * 16 + (lane & 15);
        int k   = ks * 32 + (lane >> 4) * 8 + j;
        int j32 = nst & 31;
        int d   = side ? (32 + j32) : j32;
        float v = (nst < 32) ? W_s[(l * H_DIM + k) * D_DIM + d] : W_t[(l * H_DIM + k) * D_DIM + d];
        W_stF[i] = f2bf(v);
    }
    const int total3 = E_DIM * 576;
    for (int i = idx; i < total3; i += stride) {
        int k = i % 576;
        int n = i / 576;
        float v = (k < E_DIM) ? W_res[n * E_DIM + k] : W_inp[(k - E_DIM) * E_DIM + n];
        W_packo[i] = f2h(v);
    }
    const int total4 = T_LEN * B_SZ * D_DIM;
    for (int i = idx; i < total4; i += stride)
        x_h[i] = f2h(x_seq[i]);
}

// ---- Phase 1: ESN (R8/R9 verified, byte-identical). ----
__launch_bounds__(256, 1)
__global__ void esn_kernel(const unsigned short* __restrict__ x_h,
                           const unsigned short* __restrict__ W_pack,
                           unsigned short* __restrict__ h_store /*bf16 [tc][B][E]*/,
                           unsigned short* __restrict__ h_buf   /*fp16 [2][B][E]*/,
                           unsigned int* __restrict__ ctr,
                           int t0, int tc) {
    const int bid  = blockIdx.x;
    const int g    = bid & 15;
    const int m    = bid >> 4;
    const int tid  = threadIdx.x;
    const int wave = tid >> 6;
    const int lane = tid & 63;
    const int arow = lane & 15;
    const int kq   = lane >> 4;
    const int r0   = g * 16;
    const int n0   = m * 64;
    const size_t HB = (size_t)B_SZ * E_DIM;
    unsigned int* gctr = ctr + g * 32;

    extern __shared__ char smem[];
    char* Wlb = smem;                 // [64][1152B] W-slice, swizzled
    char* hAb = smem + 64 * ROWB;     // [16][1152B] = [h(1024B) | x(128B)], swizzled

    {   // W-slice -> LDS (swizzled write; one-time)
        const int r  = tid & 63;
        const int c0 = (tid >> 6) * 18;
        #pragma unroll
        for (int u = 0; u < 18; ++u) {
            const int byte = 16 * (c0 + u);
            *reinterpret_cast<uint4*>(Wlb + rswz(r, byte)) =
                *reinterpret_cast<const uint4*>(
                    reinterpret_cast<const char*>(&W_pack[(size_t)(n0 + r) * 576]) + byte);
        }
    }

    const int srow = tid >> 4;
    const int seg  = tid & 15;
    const int xrow = tid >> 2, xc = tid & 3;

    for (int tl = 0; tl < tc; ++tl) {
        const int t = t0 + tl;
        const unsigned short* hb_r = h_buf + (size_t)(t & 1) * HB;
        unsigned short*       hb_w = h_buf + (size_t)((t & 1) ^ 1) * HB;

        uint4 xa = {0,0,0,0}, xb = {0,0,0,0};
        if (tid < 64) {
            const unsigned short* xp = &x_h[((size_t)t * B_SZ + r0 + xrow) * D_DIM + xc * 16];
            xa = *reinterpret_cast<const uint4*>(xp);
            xb = *reinterpret_cast<const uint4*>(xp + 8);
        }

        if (tid == 0) {
            while (__hip_atomic_fetch_add(gctr, 0u, __ATOMIC_RELAXED,
                                          __HIP_MEMORY_SCOPE_AGENT) < 8u * (unsigned)t)
                __builtin_amdgcn_s_sleep(1);
        }
        __syncthreads();
        asm volatile("" ::: "memory");

        ull hv[8];
        const ull* hrow = reinterpret_cast<const ull*>(&hb_r[(size_t)(r0 + srow) * E_DIM]);
        #pragma unroll
        for (int q = 0; q < 4; ++q) {
            const int c = seg + 16 * q;
            hv[2*q]   = __hip_atomic_load(hrow + 2*c,     __ATOMIC_RELAXED, __HIP_MEMORY_SCOPE_SYSTEM);
            hv[2*q+1] = __hip_atomic_load(hrow + 2*c + 1, __ATOMIC_RELAXED, __HIP_MEMORY_SCOPE_SYSTEM);
        }
        #pragma unroll
        for (int q = 0; q < 4; ++q) {
            const int c = seg + 16 * q;
            uint4 pk;
            __builtin_memcpy(&pk, &hv[2*q], 16);
            *reinterpret_cast<uint4*>(hAb + rswz(srow, 16 * c)) = pk;
        }
        if (tid < 64) {
            *reinterpret_cast<uint4*>(hAb + rswz(xrow, 1024 + 32 * xc))      = xa;
            *reinterpret_cast<uint4*>(hAb + rswz(xrow, 1024 + 32 * xc + 16)) = xb;
        }
        __syncthreads();

        if (tl == 0) {
            #pragma unroll
            for (int q = 0; q < 4; ++q) {
                const int c = seg + 16 * q;
                unsigned short o[8];
                #pragma unroll
                for (int j = 0; j < 4; ++j) o[j]     = f2bf(h2f((unsigned short)(hv[2*q]   >> (16 * j))));
                #pragma unroll
                for (int j = 0; j < 4; ++j) o[4 + j] = f2bf(h2f((unsigned short)(hv[2*q+1] >> (16 * j))));
                uint4 pk;
                __builtin_memcpy(&pk, o, 16);
                *reinterpret_cast<uint4*>(&h_store[(size_t)(r0 + srow) * E_DIM + 8 * c]) = pk;
            }
        }

        f32x4 accA = (f32x4){0.f, 0.f, 0.f, 0.f};
        f32x4 accB = (f32x4){0.f, 0.f, 0.f, 0.f};
        #pragma unroll
        for (int ks = 0; ks < 18; ++ks) {
            half8 a = *reinterpret_cast<const half8*>(hAb + rswz(arow, ks * 64 + kq * 16));
            half8 b = *reinterpret_cast<const half8*>(Wlb + rswz(wave * 16 + arow, ks * 64 + kq * 16));
            if (ks & 1) accB = __builtin_amdgcn_mfma_f32_16x16x32_f16(a, b, accB, 0, 0, 0);
            else        accA = __builtin_amdgcn_mfma_f32_16x16x32_f16(a, b, accA, 0, 0, 0);
        }
        f32x4 acc = accA + accB;

        const int ncol = n0 + wave * 16 + arow;
        #pragma unroll
        for (int i = 0; i < 4; ++i) {
            const int row = r0 + kq * 4 + i;
            float hvf = fast_tanh(acc[i]);
            __hip_atomic_store(&hb_w[(size_t)row * E_DIM + ncol], f2h(hvf),
                               __ATOMIC_RELAXED, __HIP_MEMORY_SCOPE_SYSTEM);
            if (tl + 1 < tc)
                h_store[((size_t)(tl + 1) * B_SZ + row) * E_DIM + ncol] = f2bf(hvf);
        }

        asm volatile("s_waitcnt vmcnt(0)" ::: "memory");
        __syncthreads();
        if (tid == 0)
            __hip_atomic_fetch_add(gctr, 1u, __ATOMIC_RELAXED, __HIP_MEMORY_SCOPE_AGENT);
    }
}

// ---- Phase 2: flow, stage-outer with block-resident state. ----
// Block = 128 frames (8 t-rows x 16 b). h for all frames staged ONCE into
// abf[128][SA]; z in registers (thread (r8,c8) owns dims c8*8..+8 of its 4
// subtile rows). Loop: for stage { for subtile(4) } -> each stage's 278 KB W
// is read once per block and reused across 4 M=32 subtile GEMMs (R9 bodies).
__launch_bounds__(256, 1)
__global__ void flow_kernel(const float* __restrict__ x_seq, const unsigned short* __restrict__ h_store,
                            const unsigned short* __restrict__ W_inF, const unsigned short* __restrict__ W_stF,
                            const float* __restrict__ b_in, const float* __restrict__ b_s,
                            const float* __restrict__ b_t, const float* __restrict__ rescale_w,
                            const int* __restrict__ seq_len, float* __restrict__ ll_part,
                            int t0, int tc) {
    const int ttb  = blockIdx.x >> 4;
    const int bt   = blockIdx.x & 15;
    const int tid  = threadIdx.x;
    const int wave = tid >> 6;
    const int lane = tid & 63;

    extern __shared__ char smemf[];
    unsigned short* abf   = reinterpret_cast<unsigned short*>(smemf);   // [128][SA]
    unsigned short* hidbf = abf + 128 * SA;                             // [32][SH]
    float* llacc = reinterpret_cast<float*>(hidbf + 32 * SH);           // [128]
    float* stf   = reinterpret_cast<float*>(hidbf);                     // [32][SF] alias

    const int r8 = tid >> 3;    // subtile-local row 0..31
    const int c8 = tid & 7;     // owns dims c8*8 .. c8*8+7

    float z[4][8];
    // one-time staging: x -> z regs, h -> abf h-part (all 4 subtiles)
    #pragma unroll
    for (int s = 0; s < 4; ++s) {
        const int trow = ttb * 8 + 2 * s + (r8 >> 4);
        const int brow = bt * 16 + (r8 & 15);
        const float* xp = &x_seq[((size_t)(t0 + trow) * B_SZ + brow) * D_DIM + c8 * 8];
        float4 v0 = *reinterpret_cast<const float4*>(xp);
        float4 v1 = *reinterpret_cast<const float4*>(xp + 4);
        z[s][0] = v0.x; z[s][1] = v0.y; z[s][2] = v0.z; z[s][3] = v0.w;
        z[s][4] = v1.x; z[s][5] = v1.y; z[s][6] = v1.z; z[s][7] = v1.w;
        const unsigned short* hp = &h_store[((size_t)trow * B_SZ + brow) * E_DIM + c8 * 64];
        unsigned short* ap = &abf[(s * 32 + r8) * SA + 32 + c8 * 64];
        #pragma unroll
        for (int q = 0; q < 8; ++q)
            *reinterpret_cast<uint4*>(ap + q * 8) = *reinterpret_cast<const uint4*>(hp + q * 8);
    }
    if (tid < 128) llacc[tid] = 0.f;
    __syncthreads();

    for (int stage = 0; stage < 8; ++stage) {
        const int l = 3 - (stage >> 1);
        const int side = stage & 1;
        const int ls = l * 2 + side;

        for (int s = 0; s < 4; ++s) {
            {   // abf z-build: active half writes its 8 kept-dim cols (thread-local z)
                const bool act = side ? (c8 < 4) : (c8 >= 4);
                if (act) {
                    unsigned short o[8];
                    #pragma unroll
                    for (int q = 0; q < 8; ++q) o[q] = f2bf(z[s][q]);
                    const int k = side ? (c8 * 8) : ((c8 - 4) * 8);
                    uint4 pk;
                    __builtin_memcpy(&pk, o, 16);
                    *reinterpret_cast<uint4*>(&abf[(s * 32 + r8) * SA + k]) = pk;
                }
            }
            __syncthreads();

            // hid GEMM: M=32 K=544 N=256 (R9 body; abf base = s*32*SA)
            const int base0 = s * 32 * SA;
            const unsigned short* wbase =
                W_inF + ((size_t)(ls * 16 + wave * 4) * 17) * 512 + lane * 8;
            f32x4 acc[2][4];
            #pragma unroll
            for (int mt = 0; mt < 2; ++mt)
                #pragma unroll
                for (int nt = 0; nt < 4; ++nt)
                    acc[mt][nt] = (f32x4){0.f, 0.f, 0.f, 0.f};
            const int aoff = (lane & 15) * SA + 8 * (lane >> 4);
            short8 bb[6][4];
            #pragma unroll
            for (int p = 0; p < 6; ++p)
                #pragma unroll
                for (int nt = 0; nt < 4; ++nt)
                    bb[p][nt] = *reinterpret_cast<const short8*>(wbase + (size_t)nt * 8704 + p * 512);
            #pragma unroll
            for (int ks = 0; ks < 17; ++ks) {
                const int k0 = ks * 32;
                short8 a0 = *reinterpret_cast<const short8*>(&abf[base0 + aoff + k0]);
                short8 a1 = *reinterpret_cast<const short8*>(&abf[base0 + 16 * SA + aoff + k0]);
                #pragma unroll
                for (int nt = 0; nt < 4; ++nt) {
                    acc[0][nt] = __builtin_amdgcn_mfma_f32_16x16x32_bf16(a0, bb[ks % 6][nt], acc[0][nt], 0, 0, 0);
                    acc[1][nt] = __builtin_amdgcn_mfma_f32_16x16x32_bf16(a1, bb[ks % 6][nt], acc[1][nt], 0, 0, 0);
                }
                if (ks + 6 < 17) {
                    #pragma unroll
                    for (int nt = 0; nt < 4; ++nt)
                        bb[ks % 6][nt] = *reinterpret_cast<const short8*>(
                            wbase + (size_t)nt * 8704 + (ks + 6) * 512);
                }
            }
            #pragma unroll
            for (int mt = 0; mt < 2; ++mt)
                #pragma unroll
                for (int nt = 0; nt < 4; ++nt) {
                    const int n = wave * 64 + nt * 16 + (lane & 15);
                    const float bias = b_in[l * H_DIM + n];
                    #pragma unroll
                    for (int i = 0; i < 4; ++i) {
                        const int row = mt * 16 + (lane >> 4) * 4 + i;
                        hidbf[row * SH + n] = f2bf(fast_tanh(acc[mt][nt][i] + bias));
                    }
                }
            __syncthreads();

            // slope|intercept GEMM: M=32 K=256 N=64 (R9 body)
            const unsigned short* wstb =
                W_stF + ((size_t)(ls * 4 + wave) * 8) * 512 + lane * 8;
            f32x4 acc2[2];
            acc2[0] = (f32x4){0.f,0.f,0.f,0.f};
            acc2[1] = (f32x4){0.f,0.f,0.f,0.f};
            const int hoff = (lane & 15) * SH + 8 * (lane >> 4);
            const int nst  = wave * 16 + (lane & 15);
            short8 bs0 = *reinterpret_cast<const short8*>(wstb);
            #pragma unroll
            for (int ks = 0; ks < 8; ++ks) {
                short8 bcur = bs0;
                if (ks + 1 < 8) bs0 = *reinterpret_cast<const short8*>(wstb + (ks + 1) * 512);
                const int k0 = ks * 32;
                short8 a0 = *reinterpret_cast<const short8*>(&hidbf[hoff + k0]);
                short8 a1 = *reinterpret_cast<const short8*>(&hidbf[16 * SH + hoff + k0]);
                acc2[0] = __builtin_amdgcn_mfma_f32_16x16x32_bf16(a0, bcur, acc2[0], 0, 0, 0);
                acc2[1] = __builtin_amdgcn_mfma_f32_16x16x32_bf16(a1, bcur, acc2[1], 0, 0, 0);
            }
            __syncthreads();   // hidbf reads done before stf (alias) writes
            {
                const int j = nst & 31;
                const int d = side ? (32 + j) : j;
                const bool is_s = (nst < 32);
                const float bias = is_s ? b_s[l * D_DIM + d] : b_t[l * D_DIM + d];
                const float rs = rescale_w[d];
                #pragma unroll
                for (int mt = 0; mt < 2; ++mt)
                    #pragma unroll
                    for (int i = 0; i < 4; ++i) {
                        const int row = mt * 16 + (lane >> 4) * 4 + i;
                        const float v = acc2[mt][i] + bias;
                        stf[row * SF + nst] = is_s ? (fast_tanh(v) * rs) : v;
                    }
            }
            __syncthreads();
            {   // z-update + log-det: active half (owners of updated dims), thread-local z
                const bool act = side ? (c8 >= 4) : (c8 < 4);
                if (act) {
                    const int jb = (c8 & 3) * 8;
                    float p = 0.f;
                    #pragma unroll
                    for (int q = 0; q < 8; ++q) {
                        const float sv = stf[r8 * SF + jb + q];
                        const float iv = stf[r8 * SF + 32 + jb + q];
                        z[s][q] = (z[s][q] - iv) * __expf(-sv);
                        p += sv;
                    }
                    p += __shfl_xor(p, 1);
                    p += __shfl_xor(p, 2);
                    if ((c8 & 3) == 0) llacc[s * 32 + r8] -= p;
                }
            }
            // no trailing sync needed: next iter's post-build sync precedes any
            // hidbf/stf overwrite.
        } // subtile
    } // stage

    __syncthreads();
    {   // finalize: zsum + mask per frame
        #pragma unroll
        for (int s = 0; s < 4; ++s) {
            float zs = 0.f;
            #pragma unroll
            for (int q = 0; q < 8; ++q) zs += z[s][q] * z[s][q];
            zs += __shfl_xor(zs, 1);
            zs += __shfl_xor(zs, 2);
            zs += __shfl_xor(zs, 4);
            if (c8 == 0) {
                const int trow = ttb * 8 + 2 * s + (r8 >> 4);
                const int brow = bt * 16 + (r8 & 15);
                float ll = llacc[s * 32 + r8] - 0.5f * zs - 58.812066125f;  // 0.5*64*log(2*pi)
                llacc[s * 32 + r8] = ((t0 + trow) < seq_len[brow]) ? ll : 0.f;
            }
        }
    }
    __syncthreads();
    if (tid < 16) {
        float acc = 0.f;
        #pragma unroll
        for (int s = 0; s < 4; ++s)
            acc += llacc[s * 32 + tid] + llacc[s * 32 + 16 + tid];
        ll_part[((size_t)((t0 >> 3) + ttb)) * B_SZ + bt * 16 + tid] = acc;
    }
}

__global__ void reduce_kernel(const float* __restrict__ ll_part, float* __restrict__ out) {
    int b = threadIdx.x;
    float s = 0.f;
    #pragma unroll
    for (int tt = 0; tt < T_LEN / 8; ++tt) s += ll_part[tt * B_SZ + b];
    out[b] = s;
}

extern "C" void kernel_launch(void* const* d_in, const int* in_sizes, int n_in,
                              void* d_out, int out_size, void* d_ws, size_t ws_size,
                              hipStream_t stream) {
    const float* x_seq   = (const float*)d_in[0];
    const int*   seqlen  = (const int*)d_in[1];
    const float* W_in    = (const float*)d_in[3];
    const float* b_in    = (const float*)d_in[4];
    const float* W_s     = (const float*)d_in[5];
    const float* b_s     = (const float*)d_in[6];
    const float* W_t     = (const float*)d_in[7];
    const float* b_t     = (const float*)d_in[8];
    const float* rescale = (const float*)d_in[9];
    const float* W_res   = (const float*)d_in[10];
    const float* W_inp   = (const float*)d_in[11];

    char* ws = (char*)d_ws;
    size_t off = 0;
    unsigned short* W_inF  = (unsigned short*)(ws + off); off += (size_t)8 * 16 * 17 * 64 * 8 * 2;
    unsigned short* W_stF  = (unsigned short*)(ws + off); off += (size_t)8 * 4 * 8 * 64 * 8 * 2;
    unsigned short* W_pack = (unsigned short*)(ws + off); off += (size_t)E_DIM * 576 * 2;
    unsigned short* x_h    = (unsigned short*)(ws + off); off += (size_t)T_LEN * B_SZ * D_DIM * 2;
    float* ll_part = (float*)(ws + off); off += (size_t)(T_LEN / 8) * B_SZ * 4;
    unsigned short* h_buf  = (unsigned short*)(ws + off); off += (size_t)2 * B_SZ * E_DIM * 2;
    unsigned int* ctr = (unsigned int*)(ws + off); off += (size_t)16 * 32 * 4;
    unsigned short* h_store = (unsigned short*)(ws + off);

    size_t per_t = (size_t)B_SZ * E_DIM * 2;
    size_t rem = (ws_size > off) ? (ws_size - off) : 0;
    long long tcl = (long long)(rem / per_t);
    int tc = (int)((tcl > T_LEN) ? T_LEN : tcl);
    tc &= ~15;
    if (tc < 16) tc = 16;

    hipMemsetAsync(h_buf, 0, (size_t)2 * B_SZ * E_DIM * 2, stream);
    hipMemsetAsync(ctr, 0, (size_t)16 * 32 * 4, stream);

    prep_kernel<<<2048, 256, 0, stream>>>(W_in, W_s, W_t, W_res, W_inp, x_seq,
                                          W_inF, W_stF, W_pack, x_h);
    const int esn_lds = (64 + 16) * ROWB;   // 92,160 B
    for (int t0 = 0; t0 < T_LEN; t0 += tc) {
        int cur = T_LEN - t0; if (cur > tc) cur = tc;
        esn_kernel<<<128, 256, esn_lds, stream>>>(x_h, W_pack, h_store, h_buf, ctr, t0, cur);
        flow_kernel<<<(cur / 8) * 16, 256, FLOW_LDS, stream>>>(x_seq, h_store, W_inF, W_stF,
                                                               b_in, b_s, b_t, rescale, seqlen,
                                                               ll_part, t0, cur);
    }
    reduce_kernel<<<1, B_SZ, 0, stream>>>(ll_part, (float*)d_out);
}

// Round 14
// 3614.891 us; speedup vs baseline: 1.3368x; 1.1080x over previous
//
#include <hip/hip_runtime.h>

#define T_LEN 1024
#define B_SZ  256
#define D_DIM 64
#define E_DIM 512
#define H_DIM 256

#define SA 552   // flow A-tile LDS stride (bf16 elems) — verified 2-way max
#define SH 264   // flow hid-tile LDS stride
#define SF 66    // flow stf stride (floats)
#define ROWB 1152  // esn LDS row stride BYTES (576 fp16)

#define FLOW_LDS (32*SA*2 + 32*SH*2 + 32*4)   // 52,352 B -> 3 blocks/CU

using short8 = __attribute__((ext_vector_type(8))) short;
using half8  = __attribute__((ext_vector_type(8))) _Float16;
using f32x4  = __attribute__((ext_vector_type(4))) float;
typedef unsigned long long ull;

static __device__ __forceinline__ unsigned short f2bf(float v) {
    unsigned u = __float_as_uint(v);
    u += 0x7FFFu + ((u >> 16) & 1u);   // RNE to bf16
    return (unsigned short)(u >> 16);
}
static __device__ __forceinline__ unsigned short f2h(float v) {
    _Float16 h = (_Float16)v;
    unsigned short u;
    __builtin_memcpy(&u, &h, 2);
    return u;
}
static __device__ __forceinline__ float h2f(unsigned short u) {
    _Float16 h;
    __builtin_memcpy(&h, &u, 2);
    return (float)h;
}
static __device__ __forceinline__ float fast_tanh(float x) {
    x = fminf(15.f, fmaxf(-15.f, x));
    float e = __expf(2.f * x);
    return (e - 1.f) / (e + 1.f);
}
// XOR bank swizzle within each 128B sub-block of a 1152B row (both-sides involution).
static __device__ __forceinline__ int rswz(int row, int byte_in_row) {
    return row * ROWB + (byte_in_row ^ ((row & 7) << 4));
}

// ---- Weight prep (R9 verified) ----
__global__ void prep_kernel(const float* __restrict__ W_in, const float* __restrict__ W_s,
                            const float* __restrict__ W_t, const float* __restrict__ W_res,
                            const float* __restrict__ W_inp, const float* __restrict__ x_seq,
                            unsigned short* __restrict__ W_inF, unsigned short* __restrict__ W_stF,
                            unsigned short* __restrict__ W_packo, unsigned short* __restrict__ x_h) {
    int idx = blockIdx.x * blockDim.x + threadIdx.x;
    int stride = gridDim.x * blockDim.x;
    const int total1 = 8 * 16 * 17 * 64 * 8;        // W_inF
    for (int i = idx; i < total1; i += stride) {
        int j    = i & 7;
        int lane = (i >> 3) & 63;
        int ks   = (i >> 9) % 17;
        int nt   = (i / (512 * 17)) & 15;
        int ls   = i / (512 * 17 * 16);
        int side = ls & 1, l = ls >> 1;
        int n = nt * 16 + (lane & 15);
        int k = ks * 32 + (lane >> 4) * 8 + j;
        int ksrc = (k < 32) ? (side == 0 ? 32 + k : k) : (k + 32);
        W_inF[i] = f2bf(W_in[(l * 576 + ksrc) * H_DIM + n]);
    }
    const int total2 = 8 * 4 * 8 * 64 * 8;          // W_stF
    for (int i = idx; i < total2; i += stride) {
        int j    = i & 7;
        int lane = (i >> 3) & 63;
        int ks   = (i >> 9) & 7;
        int nt   = (i >> 12) & 3;
        int ls   = i >> 14;
        int side = ls & 1, l = ls >> 1;
        int nst = nt * 16 + (lane & 15);
        int k   = ks * 32 + (lane >> 4) * 8 + j;
        int j32 = nst & 31;
        int d   = side ? (32 + j32) : j32;
        float v = (nst < 32) ? W_s[(l * H_DIM + k) * D_DIM + d] : W_t[(l * H_DIM + k) * D_DIM + d];
        W_stF[i] = f2bf(v);
    }
    const int total3 = E_DIM * 576;
    for (int i = idx; i < total3; i += stride) {
        int k = i % 576;
        int n = i / 576;
        float v = (k < E_DIM) ? W_res[n * E_DIM + k] : W_inp[(k - E_DIM) * E_DIM + n];
        W_packo[i] = f2h(v);
    }
    const int total4 = T_LEN * B_SZ * D_DIM;
    for (int i = idx; i < total4; i += stride)
        x_h[i] = f2h(x_seq[i]);
}

// ---- Phase 1: ESN (R8/R9 verified, byte-identical). ----
__launch_bounds__(256, 1)
__global__ void esn_kernel(const unsigned short* __restrict__ x_h,
                           const unsigned short* __restrict__ W_pack,
                           unsigned short* __restrict__ h_store /*bf16 [tc][B][E]*/,
                           unsigned short* __restrict__ h_buf   /*fp16 [2][B][E]*/,
                           unsigned int* __restrict__ ctr,
                           int t0, int tc) {
    const int bid  = blockIdx.x;
    const int g    = bid & 15;
    const int m    = bid >> 4;
    const int tid  = threadIdx.x;
    const int wave = tid >> 6;
    const int lane = tid & 63;
    const int arow = lane & 15;
    const int kq   = lane >> 4;
    const int r0   = g * 16;
    const int n0   = m * 64;
    const size_t HB = (size_t)B_SZ * E_DIM;
    unsigned int* gctr = ctr + g * 32;

    extern __shared__ char smem[];
    char* Wlb = smem;                 // [64][1152B] W-slice, swizzled
    char* hAb = smem + 64 * ROWB;     // [16][1152B] = [h(1024B) | x(128B)], swizzled

    {   // W-slice -> LDS (swizzled write; one-time)
        const int r  = tid & 63;
        const int c0 = (tid >> 6) * 18;
        #pragma unroll
        for (int u = 0; u < 18; ++u) {
            const int byte = 16 * (c0 + u);
            *reinterpret_cast<uint4*>(Wlb + rswz(r, byte)) =
                *reinterpret_cast<const uint4*>(
                    reinterpret_cast<const char*>(&W_pack[(size_t)(n0 + r) * 576]) + byte);
        }
    }

    const int srow = tid >> 4;
    const int seg  = tid & 15;
    const int xrow = tid >> 2, xc = tid & 3;

    for (int tl = 0; tl < tc; ++tl) {
        const int t = t0 + tl;
        const unsigned short* hb_r = h_buf + (size_t)(t & 1) * HB;
        unsigned short*       hb_w = h_buf + (size_t)((t & 1) ^ 1) * HB;

        uint4 xa = {0,0,0,0}, xb = {0,0,0,0};
        if (tid < 64) {
            const unsigned short* xp = &x_h[((size_t)t * B_SZ + r0 + xrow) * D_DIM + xc * 16];
            xa = *reinterpret_cast<const uint4*>(xp);
            xb = *reinterpret_cast<const uint4*>(xp + 8);
        }

        if (tid == 0) {
            while (__hip_atomic_fetch_add(gctr, 0u, __ATOMIC_RELAXED,
                                          __HIP_MEMORY_SCOPE_AGENT) < 8u * (unsigned)t)
                __builtin_amdgcn_s_sleep(1);
        }
        __syncthreads();
        asm volatile("" ::: "memory");

        ull hv[8];
        const ull* hrow = reinterpret_cast<const ull*>(&hb_r[(size_t)(r0 + srow) * E_DIM]);
        #pragma unroll
        for (int q = 0; q < 4; ++q) {
            const int c = seg + 16 * q;
            hv[2*q]   = __hip_atomic_load(hrow + 2*c,     __ATOMIC_RELAXED, __HIP_MEMORY_SCOPE_SYSTEM);
            hv[2*q+1] = __hip_atomic_load(hrow + 2*c + 1, __ATOMIC_RELAXED, __HIP_MEMORY_SCOPE_SYSTEM);
        }
        #pragma unroll
        for (int q = 0; q < 4; ++q) {
            const int c = seg + 16 * q;
            uint4 pk;
            __builtin_memcpy(&pk, &hv[2*q], 16);
            *reinterpret_cast<uint4*>(hAb + rswz(srow, 16 * c)) = pk;
        }
        if (tid < 64) {
            *reinterpret_cast<uint4*>(hAb + rswz(xrow, 1024 + 32 * xc))      = xa;
            *reinterpret_cast<uint4*>(hAb + rswz(xrow, 1024 + 32 * xc + 16)) = xb;
        }
        __syncthreads();

        if (tl == 0) {
            #pragma unroll
            for (int q = 0; q < 4; ++q) {
                const int c = seg + 16 * q;
                unsigned short o[8];
                #pragma unroll
                for (int j = 0; j < 4; ++j) o[j]     = f2bf(h2f((unsigned short)(hv[2*q]   >> (16 * j))));
                #pragma unroll
                for (int j = 0; j < 4; ++j) o[4 + j] = f2bf(h2f((unsigned short)(hv[2*q+1] >> (16 * j))));
                uint4 pk;
                __builtin_memcpy(&pk, o, 16);
                *reinterpret_cast<uint4*>(&h_store[(size_t)(r0 + srow) * E_DIM + 8 * c]) = pk;
            }
        }

        f32x4 accA = (f32x4){0.f, 0.f, 0.f, 0.f};
        f32x4 accB = (f32x4){0.f, 0.f, 0.f, 0.f};
        #pragma unroll
        for (int ks = 0; ks < 18; ++ks) {
            half8 a = *reinterpret_cast<const half8*>(hAb + rswz(arow, ks * 64 + kq * 16));
            half8 b = *reinterpret_cast<const half8*>(Wlb + rswz(wave * 16 + arow, ks * 64 + kq * 16));
            if (ks & 1) accB = __builtin_amdgcn_mfma_f32_16x16x32_f16(a, b, accB, 0, 0, 0);
            else        accA = __builtin_amdgcn_mfma_f32_16x16x32_f16(a, b, accA, 0, 0, 0);
        }
        f32x4 acc = accA + accB;

        const int ncol = n0 + wave * 16 + arow;
        #pragma unroll
        for (int i = 0; i < 4; ++i) {
            const int row = r0 + kq * 4 + i;
            float hvf = fast_tanh(acc[i]);
            __hip_atomic_store(&hb_w[(size_t)row * E_DIM + ncol], f2h(hvf),
                               __ATOMIC_RELAXED, __HIP_MEMORY_SCOPE_SYSTEM);
            if (tl + 1 < tc)
                h_store[((size_t)(tl + 1) * B_SZ + row) * E_DIM + ncol] = f2bf(hvf);
        }

        asm volatile("s_waitcnt vmcnt(0)" ::: "memory");
        __syncthreads();
        if (tid == 0)
            __hip_atomic_fetch_add(gctr, 1u, __ATOMIC_RELAXED, __HIP_MEMORY_SCOPE_AGENT);
    }
}

// ---- Phase 2: flow, one M=32 subtile per block, z-in-regs (R13-verified
// plumbing), 52.4 KB LDS -> 3 blocks/CU (12 waves/CU). GEMM bodies = R9. ----
__launch_bounds__(256, 3)
__global__ void flow_kernel(const float* __restrict__ x_seq, const unsigned short* __restrict__ h_store,
                            const unsigned short* __restrict__ W_inF, const unsigned short* __restrict__ W_stF,
                            const float* __restrict__ b_in, const float* __restrict__ b_s,
                            const float* __restrict__ b_t, const float* __restrict__ rescale_w,
                            const int* __restrict__ seq_len, float* __restrict__ ll_part,
                            int t0, int tc) {
    const int ttb  = blockIdx.x >> 4;    // t-pair index (2 t-rows per block)
    const int bt   = blockIdx.x & 15;
    const int tid  = threadIdx.x;
    const int wave = tid >> 6;
    const int lane = tid & 63;

    extern __shared__ char smemf[];
    unsigned short* abf   = reinterpret_cast<unsigned short*>(smemf);   // [32][SA]
    unsigned short* hidbf = abf + 32 * SA;                              // [32][SH]
    float* llacc = reinterpret_cast<float*>(hidbf + 32 * SH);           // [32]
    float* stf   = reinterpret_cast<float*>(hidbf);                     // [32][SF] alias

    const int r8 = tid >> 3;    // row 0..31
    const int c8 = tid & 7;     // owns dims c8*8 .. c8*8+7

    const int trow = ttb * 2 + (r8 >> 4);
    const int brow = bt * 16 + (r8 & 15);

    float z[8];
    {   // one-time staging: x -> z regs, h -> abf h-part
        const float* xp = &x_seq[((size_t)(t0 + trow) * B_SZ + brow) * D_DIM + c8 * 8];
        float4 v0 = *reinterpret_cast<const float4*>(xp);
        float4 v1 = *reinterpret_cast<const float4*>(xp + 4);
        z[0] = v0.x; z[1] = v0.y; z[2] = v0.z; z[3] = v0.w;
        z[4] = v1.x; z[5] = v1.y; z[6] = v1.z; z[7] = v1.w;
        const unsigned short* hp = &h_store[((size_t)trow * B_SZ + brow) * E_DIM + c8 * 64];
        unsigned short* ap = &abf[r8 * SA + 32 + c8 * 64];
        #pragma unroll
        for (int q = 0; q < 8; ++q)
            *reinterpret_cast<uint4*>(ap + q * 8) = *reinterpret_cast<const uint4*>(hp + q * 8);
    }
    if (tid < 32) llacc[tid] = 0.f;
    __syncthreads();

    for (int stage = 0; stage < 8; ++stage) {
        const int l = 3 - (stage >> 1);
        const int side = stage & 1;
        const int ls = l * 2 + side;

        {   // abf z-build: active half writes its 8 kept-dim cols (thread-local z)
            const bool act = side ? (c8 < 4) : (c8 >= 4);
            if (act) {
                unsigned short o[8];
                #pragma unroll
                for (int q = 0; q < 8; ++q) o[q] = f2bf(z[q]);
                const int k = side ? (c8 * 8) : ((c8 - 4) * 8);
                uint4 pk;
                __builtin_memcpy(&pk, o, 16);
                *reinterpret_cast<uint4*>(&abf[r8 * SA + k]) = pk;
            }
        }
        __syncthreads();

        // hid GEMM: M=32 K=544 N=256 (R9 body)
        const unsigned short* wbase =
            W_inF + ((size_t)(ls * 16 + wave * 4) * 17) * 512 + lane * 8;
        f32x4 acc[2][4];
        #pragma unroll
        for (int mt = 0; mt < 2; ++mt)
            #pragma unroll
            for (int nt = 0; nt < 4; ++nt)
                acc[mt][nt] = (f32x4){0.f, 0.f, 0.f, 0.f};
        const int aoff = (lane & 15) * SA + 8 * (lane >> 4);
        short8 bb[6][4];
        #pragma unroll
        for (int p = 0; p < 6; ++p)
            #pragma unroll
            for (int nt = 0; nt < 4; ++nt)
                bb[p][nt] = *reinterpret_cast<const short8*>(wbase + (size_t)nt * 8704 + p * 512);
        #pragma unroll
        for (int ks = 0; ks < 17; ++ks) {
            const int k0 = ks * 32;
            short8 a0 = *reinterpret_cast<const short8*>(&abf[aoff + k0]);
            short8 a1 = *reinterpret_cast<const short8*>(&abf[16 * SA + aoff + k0]);
            #pragma unroll
            for (int nt = 0; nt < 4; ++nt) {
                acc[0][nt] = __builtin_amdgcn_mfma_f32_16x16x32_bf16(a0, bb[ks % 6][nt], acc[0][nt], 0, 0, 0);
                acc[1][nt] = __builtin_amdgcn_mfma_f32_16x16x32_bf16(a1, bb[ks % 6][nt], acc[1][nt], 0, 0, 0);
            }
            if (ks + 6 < 17) {
                #pragma unroll
                for (int nt = 0; nt < 4; ++nt)
                    bb[ks % 6][nt] = *reinterpret_cast<const short8*>(
                        wbase + (size_t)nt * 8704 + (ks + 6) * 512);
            }
        }
        #pragma unroll
        for (int mt = 0; mt < 2; ++mt)
            #pragma unroll
            for (int nt = 0; nt < 4; ++nt) {
                const int n = wave * 64 + nt * 16 + (lane & 15);
                const float bias = b_in[l * H_DIM + n];
                #pragma unroll
                for (int i = 0; i < 4; ++i) {
                    const int row = mt * 16 + (lane >> 4) * 4 + i;
                    hidbf[row * SH + n] = f2bf(fast_tanh(acc[mt][nt][i] + bias));
                }
            }
        __syncthreads();

        // slope|intercept GEMM: M=32 K=256 N=64 (R9 body)
        const unsigned short* wstb =
            W_stF + ((size_t)(ls * 4 + wave) * 8) * 512 + lane * 8;
        f32x4 acc2[2];
        acc2[0] = (f32x4){0.f,0.f,0.f,0.f};
        acc2[1] = (f32x4){0.f,0.f,0.f,0.f};
        const int hoff = (lane & 15) * SH + 8 * (lane >> 4);
        const int nst  = wave * 16 + (lane & 15);
        short8 bs0 = *reinterpret_cast<const short8*>(wstb);
        #pragma unroll
        for (int ks = 0; ks < 8; ++ks) {
            short8 bcur = bs0;
            if (ks + 1 < 8) bs0 = *reinterpret_cast<const short8*>(wstb + (ks + 1) * 512);
            const int k0 = ks * 32;
            short8 a0 = *reinterpret_cast<const short8*>(&hidbf[hoff + k0]);
            short8 a1 = *reinterpret_cast<const short8*>(&hidbf[16 * SH + hoff + k0]);
            acc2[0] = __builtin_amdgcn_mfma_f32_16x16x32_bf16(a0, bcur, acc2[0], 0, 0, 0);
            acc2[1] = __builtin_amdgcn_mfma_f32_16x16x32_bf16(a1, bcur, acc2[1], 0, 0, 0);
        }
        __syncthreads();   // hidbf reads done before stf (alias) writes
        {
            const int j = nst & 31;
            const int d = side ? (32 + j) : j;
            const bool is_s = (nst < 32);
            const float bias = is_s ? b_s[l * D_DIM + d] : b_t[l * D_DIM + d];
            const float rs = rescale_w[d];
            #pragma unroll
            for (int mt = 0; mt < 2; ++mt)
                #pragma unroll
                for (int i = 0; i < 4; ++i) {
                    const int row = mt * 16 + (lane >> 4) * 4 + i;
                    const float v = acc2[mt][i] + bias;
                    stf[row * SF + nst] = is_s ? (fast_tanh(v) * rs) : v;
                }
        }
        __syncthreads();
        {   // z-update + log-det: active half (owners of updated dims), thread-local z
            const bool act = side ? (c8 >= 4) : (c8 < 4);
            if (act) {
                const int jb = (c8 & 3) * 8;
                float p = 0.f;
                #pragma unroll
                for (int q = 0; q < 8; ++q) {
                    const float sv = stf[r8 * SF + jb + q];
                    const float iv = stf[r8 * SF + 32 + jb + q];
                    z[q] = (z[q] - iv) * __expf(-sv);
                    p += sv;
                }
                p += __shfl_xor(p, 1);
                p += __shfl_xor(p, 2);
                if ((c8 & 3) == 0) llacc[r8] -= p;
            }
        }
        // next iter's post-build sync precedes any hidbf/stf overwrite (R13-verified)
    } // stage

    __syncthreads();
    {   // finalize: zsum + mask per frame
        float zs = 0.f;
        #pragma unroll
        for (int q = 0; q < 8; ++q) zs += z[q] * z[q];
        zs += __shfl_xor(zs, 1);
        zs += __shfl_xor(zs, 2);
        zs += __shfl_xor(zs, 4);
        if (c8 == 0) {
            float ll = llacc[r8] - 0.5f * zs - 58.812066125f;   // 0.5*64*log(2*pi)
            llacc[r8] = ((t0 + trow) < seq_len[brow]) ? ll : 0.f;
        }
    }
    __syncthreads();
    if (tid < 16)
        ll_part[((size_t)((t0 >> 1) + ttb)) * B_SZ + bt * 16 + tid] =
            llacc[tid] + llacc[16 + tid];
}

__global__ void reduce_kernel(const float* __restrict__ ll_part, float* __restrict__ out) {
    int b = threadIdx.x;
    float s = 0.f;
    #pragma unroll
    for (int tt = 0; tt < T_LEN / 2; ++tt) s += ll_part[tt * B_SZ + b];
    out[b] = s;
}

extern "C" void kernel_launch(void* const* d_in, const int* in_sizes, int n_in,
                              void* d_out, int out_size, void* d_ws, size_t ws_size,
                              hipStream_t stream) {
    const float* x_seq   = (const float*)d_in[0];
    const int*   seqlen  = (const int*)d_in[1];
    const float* W_in    = (const float*)d_in[3];
    const float* b_in    = (const float*)d_in[4];
    const float* W_s     = (const float*)d_in[5];
    const float* b_s     = (const float*)d_in[6];
    const float* W_t     = (const float*)d_in[7];
    const float* b_t     = (const float*)d_in[8];
    const float* rescale = (const float*)d_in[9];
    const float* W_res   = (const float*)d_in[10];
    const float* W_inp   = (const float*)d_in[11];

    char* ws = (char*)d_ws;
    size_t off = 0;
    unsigned short* W_inF  = (unsigned short*)(ws + off); off += (size_t)8 * 16 * 17 * 64 * 8 * 2;
    unsigned short* W_stF  = (unsigned short*)(ws + off); off += (size_t)8 * 4 * 8 * 64 * 8 * 2;
    unsigned short* W_pack = (unsigned short*)(ws + off); off += (size_t)E_DIM * 576 * 2;
    unsigned short* x_h    = (unsigned short*)(ws + off); off += (size_t)T_LEN * B_SZ * D_DIM * 2;
    float* ll_part = (float*)(ws + off); off += (size_t)(T_LEN / 2) * B_SZ * 4;
    unsigned short* h_buf  = (unsigned short*)(ws + off); off += (size_t)2 * B_SZ * E_DIM * 2;
    unsigned int* ctr = (unsigned int*)(ws + off); off += (size_t)16 * 32 * 4;
    unsigned short* h_store = (unsigned short*)(ws + off);

    size_t per_t = (size_t)B_SZ * E_DIM * 2;
    size_t rem = (ws_size > off) ? (ws_size - off) : 0;
    long long tcl = (long long)(rem / per_t);
    int tc = (int)((tcl > T_LEN) ? T_LEN : tcl);
    tc &= ~15;
    if (tc < 16) tc = 16;

    hipMemsetAsync(h_buf, 0, (size_t)2 * B_SZ * E_DIM * 2, stream);
    hipMemsetAsync(ctr, 0, (size_t)16 * 32 * 4, stream);

    prep_kernel<<<2048, 256, 0, stream>>>(W_in, W_s, W_t, W_res, W_inp, x_seq,
                                          W_inF, W_stF, W_pack, x_h);
    const int esn_lds = (64 + 16) * ROWB;   // 92,160 B
    for (int t0 = 0; t0 < T_LEN; t0 += tc) {
        int cur = T_LEN - t0; if (cur > tc) cur = tc;
        esn_kernel<<<128, 256, esn_lds, stream>>>(x_h, W_pack, h_store, h_buf, ctr, t0, cur);
        flow_kernel<<<(cur / 2) * 16, 256, FLOW_LDS, stream>>>(x_seq, h_store, W_inF, W_stF,
                                                               b_in, b_s, b_t, rescale, seqlen,
                                                               ll_part, t0, cur);
    }
    reduce_kernel<<<1, B_SZ, 0, stream>>>(ll_part, (float*)d_out);
}